// Round 23
// baseline (31.708 us; speedup 1.0000x reference)
//
#include <hip/hip_runtime.h>
#include <stdint.h>

constexpr int Dz = 96, Hy = 160, Wx = 160;
constexpr int NVOX = Dz * Hy * Wx;

// Block tile: 32d x 8w x 8h; 8 waves; wave v computes h = h0 + v (256 voxels).
// Stage-1 footprint (6z x 9y x 56x) staged ONCE per block (53 B/voxel),
// double-buffered channels, 3 barriers total. Wave count unchanged vs r22.
constexpr int ZW = 6, YW = 9, XP = 56;
constexpr int ROWS = ZW * YW;            // 54 (z,y) rows
constexpr int NCHUNK = ROWS * 14;        // 756 16B chunks per channel plane
constexpr int PL = ROWS * XP;            // 3024 dwords per channel buffer

#define WAIT_LGKM() do { asm volatile("s_waitcnt lgkmcnt(0)" ::: "memory"); \
                         __builtin_amdgcn_sched_barrier(0); } while (0)
#define FENCE() __builtin_amdgcn_sched_barrier(0)

__global__ __launch_bounds__(512) void st_fused_kernel(
    const float* __restrict__ src,
    const float* __restrict__ flows,
    const float* __restrict__ rfp,
    float* __restrict__ out)
{
    __shared__ float bufA[PL], bufB[PL];     // 24.2 KB channel double buffer
    __shared__ float trb[8][292];            // per-wave output transpose (9.3 KB)
    const int t = threadIdx.x;
    const int lane = t & 63;
    const int v = t >> 6;                    // wave id 0..7

    // XCD-aware bijective swizzle (1200 = 8 x 150)
    const int bid = blockIdx.x;
    const int swz = (bid & 7) * 150 + (bid >> 3);
    const int wt = swz % 20;                 // w-tile (8 w)
    const int rest = swz / 20;
    const int dt = rest % 3;                 // d-tile (32 d)
    const int hq = rest / 3;                 // h-oct 0..19
    const int w0w = wt * 8, d0 = dt * 32, h0 = hq * 8;
    const int h = h0 + v;                    // this wave's h row
    const float rf = *rfp;

    const int Z0w = (19 * w0w) >> 5;         // max 90; +5 = 95 in-bounds
    const int X0 = 53 * dt;
    const int X0a = X0 & ~3;                 // max 104; +55 = 159 in-bounds
    const int YB = (159 * h0) / 160;         // rows YB..YB+8 cover h0..h0+7 (max 151+8=159)

    // ---- 2 chunk addresses/thread (16B each) + LDS dword offsets ----
    const char* ap[2];
    int loff[2];
    {
        const char* fb = (const char*)flows + ((size_t)YB * Wx + X0a) * 4;
#pragma unroll
        for (int u = 0; u < 2; ++u) {
            int c = t + u * 512;
            if (c >= NCHUNK) c = NCHUNK - 1;   // dup tail: same value to same slot, benign
            int row = c / 14, ch = c - row * 14;
            int zr = row / YW, yr = row - zr * YW;
            ap[u] = fb + ((size_t)((Z0w + zr) * Hy + yr) * Wx) * 4 + ch * 16;
            loff[u] = row * XP + ch * 4;
        }
    }

    // issue: 6 independent float4 loads; commit: stage-sum (linearity) + LDS write
    float4 rg[2][3];
    auto issue_ch = [&]() {
#pragma unroll
        for (int u = 0; u < 2; ++u) {
            rg[u][0] = *(const float4*)(ap[u]);
            rg[u][1] = *(const float4*)(ap[u] + (size_t)3 * NVOX * 4);
            rg[u][2] = *(const float4*)(ap[u] + (size_t)6 * NVOX * 4);
        }
#pragma unroll
        for (int u = 0; u < 2; ++u) ap[u] += (size_t)NVOX * 4;   // next channel
    };
    auto commit_ch = [&](float* dst) {
#pragma unroll
        for (int u = 0; u < 2; ++u) {
            float4 s;
            s.x = (rg[u][0].x + rg[u][1].x) + rg[u][2].x;
            s.y = (rg[u][0].y + rg[u][1].y) + rg[u][2].y;
            s.z = (rg[u][0].z + rg[u][1].z) + rg[u][2].z;
            s.w = (rg[u][0].w + rg[u][1].w) + rg[u][2].w;
            *(float4*)(dst + loff[u]) = s;
        }
    };

    // ---- compute mapping: lanes vary d (stage-2 x axis = stride 1) ----
    const int dl = lane & 31;
    const int half = lane >> 5;              // picks w quartet
    const int d = d0 + dl;

    const float xf = (float)(53 * d) * (1.0f / 32.0f);
    const int   x0i = (int)xf;
    const float fx  = xf - (float)x0i;
    const int   xx  = x0i - X0a;             // 0..54
    const float wxa = 1.0f - fx, wxb = fx;

    // z-row factorization (4 consecutive rows cover all 4 k's z-pairs)
    int rowoff[4];
    float wkz[4][4];
    {
        int zzk[4]; float wz0k[4], wz1k[4];
#pragma unroll
        for (int k = 0; k < 4; ++k) {
            const int w = w0w + 4 * half + k;
            const float zf = (float)(19 * w) * (1.0f / 32.0f);
            const int z0i = (int)zf;
            const float fz = zf - (float)z0i;
            zzk[k] = z0i - Z0w;              // 0..4, nondecreasing
            wz0k[k] = 1.0f - fz; wz1k[k] = fz;
        }
        const int zz0 = zzk[0];
#pragma unroll
        for (int r = 0; r < 4; ++r) {
            rowoff[r] = min(zz0 + r, ZW - 1) * (YW * XP);
#pragma unroll
            for (int k = 0; k < 4; ++k) {
                const int rel = zzk[k] - zz0;
                wkz[r][k] = (rel == r) ? wz0k[k] : ((rel == r - 1) ? wz1k[k] : 0.0f);
            }
        }
    }

    // y-interp for this wave's single h: rows yrel, yrel+1 of the footprint
    const float yf = (float)h * (159.0f / 160.0f);
    const int y0i = (int)yf;
    const float fy = yf - (float)y0i;
    const int yrel = y0i - YB;               // 0..7 (wave-uniform)
    const float wy0 = 1.0f - fy, wy1 = fy;

    // 8 row-pair LDS reads per channel
    auto compute = [&](const float* buf, float (&acc)[4]) {
#pragma unroll
        for (int yy = 0; yy < 2; ++yy) {
            const float wy = yy ? wy1 : wy0;
            float zv0 = 0.f, zv1 = 0.f, zv2 = 0.f, zv3 = 0.f;
#pragma unroll
            for (int r = 0; r < 4; ++r) {
                const float* p = buf + rowoff[r] + (yrel + yy) * XP + xx;
                const float xv = wxa * p[0] + wxb * p[1];
                zv0 += wkz[r][0] * xv;
                zv1 += wkz[r][1] * xv;
                zv2 += wkz[r][2] * xv;
                zv3 += wkz[r][3] * xv;
            }
            acc[0] += wy * zv0;
            acc[1] += wy * zv1;
            acc[2] += wy * zv2;
            acc[3] += wy * zv3;
        }
    };

    float accA[4] = {0.f, 0.f, 0.f, 0.f};
    float accB[4] = {0.f, 0.f, 0.f, 0.f};
    float accC[4] = {0.f, 0.f, 0.f, 0.f};

    // ---- 3-channel block pipeline: 3 barriers total ----
    issue_ch();                  // ch0
    commit_ch(bufA);
    __syncthreads();             // bufA visible
    issue_ch();                  // ch1 (latency hides under compute)
    compute(bufA, accA);
    FENCE();
    commit_ch(bufB);
    __syncthreads();             // bufB visible; all reads of bufA done
    issue_ch();                  // ch2
    compute(bufB, accB);
    FENCE();
    commit_ch(bufA);
    __syncthreads();             // bufA (ch2) visible
    compute(bufA, accC);

    // ---- stage 2: row-paired src sampling (zeros mode) -> wave-private transpose ----
    float* tr = &trb[v][0];
#pragma unroll
    for (int k = 0; k < 4; ++k) {
        const int w = w0w + 4 * half + k;
        const float f0 = (float)d + accA[k] * rf;    // -> x axis of src
        const float f1 = (float)h + accB[k] * rf;    // -> y axis
        const float f2 = (float)w + accC[k] * rf;    // -> z axis

        const float xs = f0 * (159.0f / 95.0f);
        const float ys = f1;
        const float zs = f2 * (95.0f / 159.0f);

        const float xf0 = floorf(xs), yf0 = floorf(ys), zf0 = floorf(zs);
        const float gx = xs - xf0, gy = ys - yf0, gz = zs - zf0;
        const int xi0 = (int)xf0, yi0 = (int)yf0, zi0 = (int)zf0;

        const int xc = min(max(xi0, 0), Wx - 2);
        const bool sx0 = (xi0 == xc);
        const float wx0m = ((unsigned)xi0 < (unsigned)Wx) ? (1.0f - gx) : 0.0f;
        const float wx1m = ((unsigned)(xi0 + 1) < (unsigned)Wx) ? gx : 0.0f;

        const int yc0 = min(max(yi0, 0), Hy - 1);
        const int yc1 = min(max(yi0 + 1, 0), Hy - 1);
        const int zc0 = min(max(zi0, 0), Dz - 1);
        const int zc1 = min(max(zi0 + 1, 0), Dz - 1);
        const float wy0m = ((unsigned)yi0 < (unsigned)Hy) ? (1.0f - gy) : 0.0f;
        const float wy1m = ((unsigned)(yi0 + 1) < (unsigned)Hy) ? gy : 0.0f;
        const float wz0m = ((unsigned)zi0 < (unsigned)Dz) ? (1.0f - gz) : 0.0f;
        const float wz1m = ((unsigned)(zi0 + 1) < (unsigned)Dz) ? gz : 0.0f;

        const float w00 = wz0m * wy0m, w01 = wz0m * wy1m;
        const float w10 = wz1m * wy0m, w11 = wz1m * wy1m;

        float r = 0.0f;
        auto rowadd = [&](int zc, int yc, float wgt) {
            const float* p = src + ((size_t)zc * Hy + yc) * Wx + xc;
            const float va = p[0], vb = p[1];
            const float s0 = sx0 ? va : vb;    // value at xi0 (xi0==159 -> vb)
            const float s1 = sx0 ? vb : va;    // value at xi1 (xi0==-1 -> va)
            r += wgt * (wx0m * s0 + wx1m * s1);
        };
        rowadd(zc0, yc0, w00);
        rowadd(zc0, yc1, w01);
        rowadd(zc1, yc0, w10);
        rowadd(zc1, yc1, w11);

        tr[dl * 9 + 4 * half + k] = r;
    }
    WAIT_LGKM();

    const int rrow = lane >> 3;              // 0..7
    const int rcol = lane & 7;               // 0..7
#pragma unroll
    for (int m = 0; m < 4; ++m) {
        const int dr = m * 8 + rrow;
        out[((size_t)(d0 + dr) * Hy + h) * Wx + (w0w + rcol)] =
            tr[dr * 9 + rcol];
    }
}

extern "C" void kernel_launch(void* const* d_in, const int* in_sizes, int n_in,
                              void* d_out, int out_size, void* d_ws, size_t ws_size,
                              hipStream_t stream) {
    const float* src   = (const float*)d_in[0];
    const float* flows = (const float*)d_in[1];
    const float* rfp   = (const float*)d_in[2];
    float* out = (float*)d_out;

    st_fused_kernel<<<dim3(1200), 512, 0, stream>>>(src, flows, rfp, out);
}

// Round 24
// 29.011 us; speedup vs baseline: 1.0930x; 1.0930x over previous
//
#include <hip/hip_runtime.h>
#include <stdint.h>

constexpr int Dz = 96, Hy = 160, Wx = 160;
constexpr int NVOX = Dz * Hy * Wx;

// Block tile: 32d x 8w x 4h; 4 waves; wave v computes h = h0 + v (256 voxels).
// Stage-1 footprint (6z x 5y x 56x) staged ONCE per block, double-buffered
// channels, 3 barriers total. Measured optimum of the design family (r22).
constexpr int ZW = 6, YW = 5, XP = 56;
constexpr int ROWS = ZW * YW;            // 30 (z,y) rows
constexpr int NCHUNK = ROWS * 14;        // 420 16B chunks per channel plane
constexpr int PL = ROWS * XP;            // 1680 dwords per channel buffer

#define WAIT_LGKM() do { asm volatile("s_waitcnt lgkmcnt(0)" ::: "memory"); \
                         __builtin_amdgcn_sched_barrier(0); } while (0)
#define FENCE() __builtin_amdgcn_sched_barrier(0)

__global__ __launch_bounds__(256) void st_fused_kernel(
    const float* __restrict__ src,
    const float* __restrict__ flows,
    const float* __restrict__ rfp,
    float* __restrict__ out)
{
    __shared__ float bufA[PL], bufB[PL];     // 13.4 KB channel double buffer
    __shared__ float trb[4][292];            // per-wave output transpose (4.7 KB)
    const int t = threadIdx.x;
    const int lane = t & 63;
    const int v = t >> 6;                    // wave id 0..3

    // XCD-aware bijective swizzle (2400 = 8 x 300)
    const int bid = blockIdx.x;
    const int swz = (bid & 7) * 300 + (bid >> 3);
    const int wt = swz % 20;                 // w-tile (8 w)
    const int rest = swz / 20;
    const int dt = rest % 3;                 // d-tile (32 d)
    const int hq = rest / 3;                 // h-quad 0..39
    const int w0w = wt * 8, d0 = dt * 32, h0 = hq * 4;
    const int h = h0 + v;                    // this wave's h row
    const float rf = *rfp;

    const int Z0w = (19 * w0w) >> 5;         // max 90; +5 = 95 in-bounds
    const int X0 = 53 * dt;
    const int X0a = X0 & ~3;                 // max 104; +55 = 159 in-bounds
    const int YB = (159 * h0) / 160;         // rows YB..YB+4 cover h0..h0+3

    // ---- 2 chunk addresses/thread (16B each) + LDS dword offsets ----
    const char* ap[2];
    int loff[2];
    {
        const char* fb = (const char*)flows + ((size_t)YB * Wx + X0a) * 4;
#pragma unroll
        for (int u = 0; u < 2; ++u) {
            int c = t + u * 256;
            if (c >= NCHUNK) c = NCHUNK - 1;   // dup tail: same value to same slot, benign
            int row = c / 14, ch = c - row * 14;
            int zr = row / YW, yr = row - zr * YW;
            ap[u] = fb + ((size_t)((Z0w + zr) * Hy + yr) * Wx) * 4 + ch * 16;
            loff[u] = row * XP + ch * 4;
        }
    }

    // issue: 6 independent float4 loads; commit: stage-sum (linearity) + LDS write
    float4 rg[2][3];
    auto issue_ch = [&]() {
#pragma unroll
        for (int u = 0; u < 2; ++u) {
            rg[u][0] = *(const float4*)(ap[u]);
            rg[u][1] = *(const float4*)(ap[u] + (size_t)3 * NVOX * 4);
            rg[u][2] = *(const float4*)(ap[u] + (size_t)6 * NVOX * 4);
        }
#pragma unroll
        for (int u = 0; u < 2; ++u) ap[u] += (size_t)NVOX * 4;   // next channel
    };
    auto commit_ch = [&](float* dst) {
#pragma unroll
        for (int u = 0; u < 2; ++u) {
            float4 s;
            s.x = (rg[u][0].x + rg[u][1].x) + rg[u][2].x;
            s.y = (rg[u][0].y + rg[u][1].y) + rg[u][2].y;
            s.z = (rg[u][0].z + rg[u][1].z) + rg[u][2].z;
            s.w = (rg[u][0].w + rg[u][1].w) + rg[u][2].w;
            *(float4*)(dst + loff[u]) = s;
        }
    };

    // ---- compute mapping: lanes vary d (stage-2 x axis = stride 1) ----
    const int dl = lane & 31;
    const int half = lane >> 5;              // picks w quartet
    const int d = d0 + dl;

    const float xf = (float)(53 * d) * (1.0f / 32.0f);
    const int   x0i = (int)xf;
    const float fx  = xf - (float)x0i;
    const int   xx  = x0i - X0a;             // 0..54
    const float wxa = 1.0f - fx, wxb = fx;

    // z-row factorization (4 consecutive rows cover all 4 k's z-pairs)
    int rowoff[4];
    float wkz[4][4];
    {
        int zzk[4]; float wz0k[4], wz1k[4];
#pragma unroll
        for (int k = 0; k < 4; ++k) {
            const int w = w0w + 4 * half + k;
            const float zf = (float)(19 * w) * (1.0f / 32.0f);
            const int z0i = (int)zf;
            const float fz = zf - (float)z0i;
            zzk[k] = z0i - Z0w;              // 0..4, nondecreasing
            wz0k[k] = 1.0f - fz; wz1k[k] = fz;
        }
        const int zz0 = zzk[0];
#pragma unroll
        for (int r = 0; r < 4; ++r) {
            rowoff[r] = min(zz0 + r, ZW - 1) * (YW * XP);
#pragma unroll
            for (int k = 0; k < 4; ++k) {
                const int rel = zzk[k] - zz0;
                wkz[r][k] = (rel == r) ? wz0k[k] : ((rel == r - 1) ? wz1k[k] : 0.0f);
            }
        }
    }

    // y-interp for this wave's single h: rows yrel, yrel+1 of the footprint
    const float yf = (float)h * (159.0f / 160.0f);
    const int y0i = (int)yf;
    const float fy = yf - (float)y0i;
    const int yrel = y0i - YB;               // 0..3 (wave-uniform)
    const float wy0 = 1.0f - fy, wy1 = fy;

    // 8 row-pair LDS reads per channel
    auto compute = [&](const float* buf, float (&acc)[4]) {
#pragma unroll
        for (int yy = 0; yy < 2; ++yy) {
            const float wy = yy ? wy1 : wy0;
            float zv0 = 0.f, zv1 = 0.f, zv2 = 0.f, zv3 = 0.f;
#pragma unroll
            for (int r = 0; r < 4; ++r) {
                const float* p = buf + rowoff[r] + (yrel + yy) * XP + xx;
                const float xv = wxa * p[0] + wxb * p[1];
                zv0 += wkz[r][0] * xv;
                zv1 += wkz[r][1] * xv;
                zv2 += wkz[r][2] * xv;
                zv3 += wkz[r][3] * xv;
            }
            acc[0] += wy * zv0;
            acc[1] += wy * zv1;
            acc[2] += wy * zv2;
            acc[3] += wy * zv3;
        }
    };

    float accA[4] = {0.f, 0.f, 0.f, 0.f};
    float accB[4] = {0.f, 0.f, 0.f, 0.f};
    float accC[4] = {0.f, 0.f, 0.f, 0.f};

    // ---- 3-channel block pipeline: 3 barriers total ----
    issue_ch();                  // ch0
    commit_ch(bufA);
    __syncthreads();             // bufA visible
    issue_ch();                  // ch1 (latency hides under compute)
    compute(bufA, accA);
    FENCE();
    commit_ch(bufB);
    __syncthreads();             // bufB visible; all reads of bufA done
    issue_ch();                  // ch2
    compute(bufB, accB);
    FENCE();
    commit_ch(bufA);
    __syncthreads();             // bufA (ch2) visible
    compute(bufA, accC);

    // ---- stage 2: row-paired src sampling (zeros mode) -> wave-private transpose ----
    float* tr = &trb[v][0];
#pragma unroll
    for (int k = 0; k < 4; ++k) {
        const int w = w0w + 4 * half + k;
        const float f0 = (float)d + accA[k] * rf;    // -> x axis of src
        const float f1 = (float)h + accB[k] * rf;    // -> y axis
        const float f2 = (float)w + accC[k] * rf;    // -> z axis

        const float xs = f0 * (159.0f / 95.0f);
        const float ys = f1;
        const float zs = f2 * (95.0f / 159.0f);

        const float xf0 = floorf(xs), yf0 = floorf(ys), zf0 = floorf(zs);
        const float gx = xs - xf0, gy = ys - yf0, gz = zs - zf0;
        const int xi0 = (int)xf0, yi0 = (int)yf0, zi0 = (int)zf0;

        const int xc = min(max(xi0, 0), Wx - 2);
        const bool sx0 = (xi0 == xc);
        const float wx0m = ((unsigned)xi0 < (unsigned)Wx) ? (1.0f - gx) : 0.0f;
        const float wx1m = ((unsigned)(xi0 + 1) < (unsigned)Wx) ? gx : 0.0f;

        const int yc0 = min(max(yi0, 0), Hy - 1);
        const int yc1 = min(max(yi0 + 1, 0), Hy - 1);
        const int zc0 = min(max(zi0, 0), Dz - 1);
        const int zc1 = min(max(zi0 + 1, 0), Dz - 1);
        const float wy0m = ((unsigned)yi0 < (unsigned)Hy) ? (1.0f - gy) : 0.0f;
        const float wy1m = ((unsigned)(yi0 + 1) < (unsigned)Hy) ? gy : 0.0f;
        const float wz0m = ((unsigned)zi0 < (unsigned)Dz) ? (1.0f - gz) : 0.0f;
        const float wz1m = ((unsigned)(zi0 + 1) < (unsigned)Dz) ? gz : 0.0f;

        const float w00 = wz0m * wy0m, w01 = wz0m * wy1m;
        const float w10 = wz1m * wy0m, w11 = wz1m * wy1m;

        float r = 0.0f;
        auto rowadd = [&](int zc, int yc, float wgt) {
            const float* p = src + ((size_t)zc * Hy + yc) * Wx + xc;
            const float va = p[0], vb = p[1];
            const float s0 = sx0 ? va : vb;    // value at xi0 (xi0==159 -> vb)
            const float s1 = sx0 ? vb : va;    // value at xi1 (xi0==-1 -> va)
            r += wgt * (wx0m * s0 + wx1m * s1);
        };
        rowadd(zc0, yc0, w00);
        rowadd(zc0, yc1, w01);
        rowadd(zc1, yc0, w10);
        rowadd(zc1, yc1, w11);

        tr[dl * 9 + 4 * half + k] = r;
    }
    WAIT_LGKM();

    const int rrow = lane >> 3;              // 0..7
    const int rcol = lane & 7;               // 0..7
#pragma unroll
    for (int m = 0; m < 4; ++m) {
        const int dr = m * 8 + rrow;
        out[((size_t)(d0 + dr) * Hy + h) * Wx + (w0w + rcol)] =
            tr[dr * 9 + rcol];
    }
}

extern "C" void kernel_launch(void* const* d_in, const int* in_sizes, int n_in,
                              void* d_out, int out_size, void* d_ws, size_t ws_size,
                              hipStream_t stream) {
    const float* src   = (const float*)d_in[0];
    const float* flows = (const float*)d_in[1];
    const float* rfp   = (const float*)d_in[2];
    float* out = (float*)d_out;

    st_fused_kernel<<<dim3(2400), 256, 0, stream>>>(src, flows, rfp, out);
}